// Round 1
// baseline (106.653 us; speedup 1.0000x reference)
//
#include <hip/hip_runtime.h>

#define HH 479
#define WW 639
#define BATCH 8
#define NBLK (20 * 30 * 8)   // 4800 blocks

// Tile: 32 cols x 16 rows per block, 256 threads, 2 px/thread.
// R11 (this round): k-PHASED cs buffer. The two inputs never need their
// column-sum records at the same time -> one cs[624*6] (15 KB) reused across
// k=0/k=1 phases. LDS 37.3 KB -> 22.4 KB => 6-7 blocks/CU (was 4);
// __launch_bounds__(256,6) raises resident waves 16->24 per CU to eat the
// barrier/latency stalls that dominate (~65% of kernel time by pipe model).
// Stage 1 re-split into 156 tasks PER PHASE via row parity (each task owns
// rows p, p+2, p+4, p+6 of its half; slide-by-2, chain length 4) so lane
// utilization matches the old 2-input split. aw2[] dropped (recompute a*a)
// to fit the 85-VGPR cap at 6 waves/EU.
// Stage 2 (R8): adjacent pixels share 7/8 window columns -> 9 shared core
// sums + 1 unique tap per pixel. Solve (f32, R5-validated): centered A_hat
// + Sherman-Morrison => same unit normal as (M+eps I)^-1 s.
// Retirement: per-block STORE into acc[block_id] (no memset), tiny finalize.
// (R2/R3: fence+counter readback poisons retirement.)

__device__ __forceinline__ void solve_normal(
    float xx, float xy, float xz, float yy, float yz, float zz,
    float xs, float ys, float zs,
    float a_c, float b_c, float d0,
    float* nx, float* ny, float* nz)
{
    const float EPSV = 1e-6f;
    const float inv64 = 1.0f / 64.0f;
    float hx = xs * inv64, hy = ys * inv64, hz = zs * inv64;
    float cxx = fmaf(-hx, xs, xx) + EPSV;
    float cxy = fmaf(-hx, ys, xy);
    float cxz = fmaf(-hx, zs, xz);
    float cyy = fmaf(-hy, ys, yy) + EPSV;
    float cyz = fmaf(-hy, zs, yz);
    float czz = fmaf(-hz, zs, zz) + EPSV;
    float c00 = fmaf(cyy, czz, -cyz * cyz);
    float c01 = fmaf(cxz, cyz, -cxy * czz);
    float c02 = fmaf(cxy, cyz, -cxz * cyy);
    float c11 = fmaf(cxx, czz, -cxz * cxz);
    float c12 = fmaf(cxy, cxz, -cxx * cyz);
    float c22 = fmaf(cxx, cyy, -cxy * cxy);
    float m0 = fmaf(c00, xs, fmaf(c01, ys, c02 * zs));
    float m1 = fmaf(c01, xs, fmaf(c11, ys, c12 * zs));
    float m2 = fmaf(c02, xs, fmaf(c12, ys, c22 * zs));
    float g  = fmaf(m0, a_c, fmaf(m1, b_c, m2));   // sign of dot(n, xyz), d0>0
    float inv = rsqrtf(fmaf(m0, m0, fmaf(m1, m1, m2 * m2)));
    if (g > 0.0f) inv = -inv;
    if (!(d0 > 0.0f)) inv = 0.0f;                  // where(depth>0, n, 0)
    *nx = m0 * inv; *ny = m1 * inv; *nz = m2 * inv;
}

__global__ __launch_bounds__(256, 6)
void ppal_main(const float* __restrict__ pred, const float* __restrict__ gt,
               double* __restrict__ acc)
{
    const int tx = threadIdx.x;        // 0..15
    const int ty = threadIdx.y;        // 0..15
    const int tid = ty * 16 + tx;
    const int j0 = blockIdx.x * 32;
    const int i0 = blockIdx.y * 16;
    const int b  = blockIdx.z;

    const float invFX = 1.0f / 518.857f;
    const float invFY = 1.0f / 519.469f;

    // depth tiles: rows i0-4..i0+18 (23), cols j0-4..j0+34 (39); stride 40
    __shared__ float sd[2][23 * 40];
    // SINGLE-k column-sum records: entry t = i*39 + c; {S1,Sb,Sbb,T1,Tb,pad}
    __shared__ float cs[624 * 6];
    __shared__ float wsum[4];

    const float* src0 = pred + (size_t)b * (HH * WW);
    const float* src1 = gt   + (size_t)b * (HH * WW);
    for (int idx = tid; idx < 23 * 40; idx += 256) {
        int lr = idx / 40, lc = idx - lr * 40;
        int r = i0 - 4 + lr, c = j0 - 4 + lc;
        bool ok = (lc < 39) && (r >= 0) && (r < HH) && (c >= 0) && (c < WW);
        int off = r * WW + c;
        sd[0][idx] = ok ? src0[off] : 0.0f;
        sd[1][idx] = ok ? src1[off] : 0.0f;
    }

    // stage-2 per-thread constants (live across both phases)
    float aw[9];
#pragma unroll
    for (int m = 0; m < 9; ++m)
        aw[m] = ((float)(j0 + 2 * tx + m - 4) - 319.5f) * invFX;
    const float bc = ((float)(i0 + ty) - 239.5f) * invFY;
    const int ebase = ty * 39 + 2 * tx;   // record entry for m=0

    float n0A[3], n1A[3];   // input-0 normals for pixels 0,1
    float contrib = 0.0f;

    __syncthreads();

#pragma unroll
    for (int k = 0; k < 2; ++k) {
        // ---- stage 1 (phase k): 156 tasks, row-parity split, slide-by-2 ----
        // task: g = tid/39 in 0..3 -> h = g>>1 (row half), p = g&1 (parity),
        // c = tid%39 (window col). Owns output rows rb, rb+2, rb+4, rb+6
        // with rb = 8h+p; window of output i = tile rows i..i+7.
        if (tid < 156) {
            int g = tid / 39;
            int c = tid - 39 * g;
            int rb = 8 * (g >> 1) + (g & 1);
            const float* col = &sd[k][c];
            float S1 = 0.f, Sb = 0.f, Sbb = 0.f, T1 = 0.f, Tb = 0.f;
#pragma unroll
            for (int r = 0; r < 8; ++r) {
                int rr = rb + r;
                float d  = col[rr * 40];
                float bv = ((float)(i0 + rr - 4) - 239.5f) * invFY;
                float bd = bv * d;
                T1 += d;  Tb += bd;
                S1  = fmaf(d,  d,  S1);
                Sb  = fmaf(bd, d,  Sb);
                Sbb = fmaf(bd, bd, Sbb);
            }
            {
                float* e = &cs[6 * (rb * 39 + c)];
                *(float2*)(e)     = make_float2(S1, Sb);
                *(float2*)(e + 2) = make_float2(Sbb, T1);
                e[4] = Tb;
            }
#pragma unroll
            for (int s = 1; s < 4; ++s) {
                int i = rb + 2 * s;
                // window slides by 2: tile rows i-2,i-1 leave; i+6,i+7 enter
                float d0a = col[(i - 2) * 40], d0b = col[(i - 1) * 40];
                float d1a = col[(i + 6) * 40], d1b = col[(i + 7) * 40];
                float b0a = ((float)(i0 + i - 6) - 239.5f) * invFY;
                float b0b = ((float)(i0 + i - 5) - 239.5f) * invFY;
                float b1a = ((float)(i0 + i + 2) - 239.5f) * invFY;
                float b1b = ((float)(i0 + i + 3) - 239.5f) * invFY;
                float bd0a = b0a * d0a, bd0b = b0b * d0b;
                float bd1a = b1a * d1a, bd1b = b1b * d1b;
                T1  += (d1a - d0a) + (d1b - d0b);
                Tb  += (bd1a - bd0a) + (bd1b - bd0b);
                S1  += fmaf(d1a, d1a, -d0a * d0a)
                     + fmaf(d1b, d1b, -d0b * d0b);
                Sb  += fmaf(bd1a, d1a, -bd0a * d0a)
                     + fmaf(bd1b, d1b, -bd0b * d0b);
                Sbb += fmaf(bd1a, bd1a, -bd0a * bd0a)
                     + fmaf(bd1b, bd1b, -bd0b * bd0b);
                float* e = &cs[6 * (i * 39 + c)];
                *(float2*)(e)     = make_float2(S1, Sb);
                *(float2*)(e + 2) = make_float2(Sbb, T1);
                e[4] = Tb;
            }
        }
        __syncthreads();

        // ---- stage 2 (phase k): shared-core combine + 2 f32 solves ----
        {
            float Sxx = 0.f, Sxy = 0.f, Sxz = 0.f, Syy = 0.f, Syz = 0.f;
            float Szz = 0.f, Sxs = 0.f, Sys = 0.f, Szs = 0.f;
#pragma unroll
            for (int m = 1; m < 8; ++m) {
                const float* e = &cs[6 * (ebase + m)];
                float2 p01 = *(const float2*)(e);       // S1, Sb
                float2 p23 = *(const float2*)(e + 2);   // Sbb, T1
                float  tb  = e[4];                      // Tb
                Szz += p01.x;  Syz += p01.y;  Syy += p23.x;
                Szs += p23.y;  Sys += tb;
                Sxz = fmaf(aw[m],         p01.x, Sxz);
                Sxy = fmaf(aw[m],         p01.y, Sxy);
                Sxs = fmaf(aw[m],         p23.y, Sxs);
                Sxx = fmaf(aw[m] * aw[m], p01.x, Sxx);
            }

            float nn[2][3];
#pragma unroll
            for (int p = 0; p < 2; ++p) {
                int m = (p == 0) ? 0 : 8;               // unique tap
                const float* e = &cs[6 * (ebase + m)];
                float2 p01 = *(const float2*)(e);
                float2 p23 = *(const float2*)(e + 2);
                float  tb  = e[4];
                float xx = fmaf(aw[m] * aw[m], p01.x, Sxx);
                float xy = fmaf(aw[m], p01.y, Sxy);
                float xz = fmaf(aw[m], p01.x, Sxz);
                float yy = Syy + p23.x;
                float yz = Syz + p01.y;
                float zz = Szz + p01.x;
                float xs = fmaf(aw[m], p23.y, Sxs);
                float ys = Sys + tb;
                float zs = Szs + p23.y;
                float d0 = sd[k][(ty + 4) * 40 + (2 * tx + p + 4)];
                solve_normal(xx, xy, xz, yy, yz, zz, xs, ys, zs,
                             aw[4 + p], bc, d0, &nn[p][0], &nn[p][1], &nn[p][2]);
            }
            if (k == 0) {
                n0A[0] = nn[0][0]; n0A[1] = nn[0][1]; n0A[2] = nn[0][2];
                n1A[0] = nn[1][0]; n1A[1] = nn[1][1]; n1A[2] = nn[1][2];
                __syncthreads();   // all cs reads done -> phase 1 may overwrite
            } else {
                const int i = i0 + ty;
                const bool valid0 = (i < HH);
                const bool valid1 = (i < HH) && (j0 + 2 * tx + 1 < WW);
                float c0 = fabsf(n0A[0] - nn[0][0]) + fabsf(n0A[1] - nn[0][1])
                         + fabsf(n0A[2] - nn[0][2]);
                float c1 = fabsf(n1A[0] - nn[1][0]) + fabsf(n1A[1] - nn[1][1])
                         + fabsf(n1A[2] - nn[1][2]);
                contrib = (valid0 ? c0 : 0.0f) + (valid1 ? c1 : 0.0f);
            }
        }
    }

    // ---- reduce: wave shuffle -> LDS -> ONE plain STORE per block ----
    float v = contrib;
#pragma unroll
    for (int off = 32; off > 0; off >>= 1) v += __shfl_down(v, off, 64);
    int wid = tid >> 6, lane = tid & 63;
    if (lane == 0) wsum[wid] = v;
    __syncthreads();
    if (tid == 0) {
        double bs = (double)wsum[0] + (double)wsum[1] + (double)wsum[2] + (double)wsum[3];
        int slot = blockIdx.x + 20 * blockIdx.y + 600 * blockIdx.z;
        acc[slot] = bs;   // unique slot, written every launch -> no memset
    }
}

__global__ void ppal_finalize(const double* __restrict__ acc, float* __restrict__ out)
{
    int tid = threadIdx.x;             // 256 threads, one block
    double v = 0.0;
    for (int s = tid; s < NBLK; s += 256) v += acc[s];
#pragma unroll
    for (int off = 32; off > 0; off >>= 1) v += __shfl_down(v, off, 64);
    __shared__ double wsum[4];
    int wid = tid >> 6, lane = tid & 63;
    if (lane == 0) wsum[wid] = v;
    __syncthreads();
    if (tid == 0)
        out[0] = (float)((wsum[0] + wsum[1] + wsum[2] + wsum[3])
                         * (1.0 / 7345944.0));  // mean over B*3*H*W
}

extern "C" void kernel_launch(void* const* d_in, const int* in_sizes, int n_in,
                              void* d_out, int out_size, void* d_ws, size_t ws_size,
                              hipStream_t stream)
{
    const float* pred = (const float*)d_in[0];
    const float* gt   = (const float*)d_in[1];
    float* out  = (float*)d_out;
    double* acc = (double*)d_ws;

    dim3 grid(20, 30, BATCH);          // 32-col x 16-row tiles = 4800 blocks
    dim3 block(16, 16);
    ppal_main<<<grid, block, 0, stream>>>(pred, gt, acc);
    ppal_finalize<<<1, 256, 0, stream>>>(acc, out);
}

// Round 2
// 99.112 us; speedup vs baseline: 1.0761x; 1.0761x over previous
//
#include <hip/hip_runtime.h>

#define HH 479
#define WW 639
#define BATCH 8
#define NBLK (20 * 30 * 8)   // 4800 blocks

// Tile: 32 cols x 16 rows per block, 256 threads, 2 px/thread.
// R12: (a) k-phased cs kept, but stage 1 now uses 4-row HALF-CHAINS with
// slide-by-1 (task = (col, 4-row group), rb = 4*(tid/39); init 8-row sum +
// 3 slide-by-1 steps) -> per-output-row cost back to R10 level (R11's
// row-parity slide-by-2 doubled it). (b) cs is SoA: 5 float arrays indexed
// e = i*39+c -> per-array tx stride 2 words, ty stride 39 (odd) => max
// 2-way LDS bank aliasing (free), vs 4-way with AoS stride-6 (3.39M
// conflict cycles/dispatch measured in R11). sd row stride 41 (odd) for the
// same reason. (c) LDS total ~20 KB -> 8 blocks/CU; __launch_bounds__(256,8)
// as occupancy diagnostic: R11 showed 48% occupancy despite 22.5 KB LDS.
// Stage 2 (R8): adjacent pixels share 7/8 window columns -> 9 shared core
// sums + 1 unique tap per pixel. Solve (f32, R5-validated): centered A_hat
// + Sherman-Morrison => same unit normal as (M+eps I)^-1 s.
// Retirement: per-block STORE into acc[block_id] (no memset), tiny finalize.
// (R2/R3: fence+counter readback poisons retirement.)

__device__ __forceinline__ void solve_normal(
    float xx, float xy, float xz, float yy, float yz, float zz,
    float xs, float ys, float zs,
    float a_c, float b_c, float d0,
    float* nx, float* ny, float* nz)
{
    const float EPSV = 1e-6f;
    const float inv64 = 1.0f / 64.0f;
    float hx = xs * inv64, hy = ys * inv64, hz = zs * inv64;
    float cxx = fmaf(-hx, xs, xx) + EPSV;
    float cxy = fmaf(-hx, ys, xy);
    float cxz = fmaf(-hx, zs, xz);
    float cyy = fmaf(-hy, ys, yy) + EPSV;
    float cyz = fmaf(-hy, zs, yz);
    float czz = fmaf(-hz, zs, zz) + EPSV;
    float c00 = fmaf(cyy, czz, -cyz * cyz);
    float c01 = fmaf(cxz, cyz, -cxy * czz);
    float c02 = fmaf(cxy, cyz, -cxz * cyy);
    float c11 = fmaf(cxx, czz, -cxz * cxz);
    float c12 = fmaf(cxy, cxz, -cxx * cyz);
    float c22 = fmaf(cxx, cyy, -cxy * cxy);
    float m0 = fmaf(c00, xs, fmaf(c01, ys, c02 * zs));
    float m1 = fmaf(c01, xs, fmaf(c11, ys, c12 * zs));
    float m2 = fmaf(c02, xs, fmaf(c12, ys, c22 * zs));
    float g  = fmaf(m0, a_c, fmaf(m1, b_c, m2));   // sign of dot(n, xyz), d0>0
    float inv = rsqrtf(fmaf(m0, m0, fmaf(m1, m1, m2 * m2)));
    if (g > 0.0f) inv = -inv;
    if (!(d0 > 0.0f)) inv = 0.0f;                  // where(depth>0, n, 0)
    *nx = m0 * inv; *ny = m1 * inv; *nz = m2 * inv;
}

__global__ __launch_bounds__(256, 8)
void ppal_main(const float* __restrict__ pred, const float* __restrict__ gt,
               double* __restrict__ acc)
{
    const int tx = threadIdx.x;        // 0..15
    const int ty = threadIdx.y;        // 0..15
    const int tid = ty * 16 + tx;
    const int j0 = blockIdx.x * 32;
    const int i0 = blockIdx.y * 16;
    const int b  = blockIdx.z;

    const float invFX = 1.0f / 518.857f;
    const float invFY = 1.0f / 519.469f;

    // depth tiles: rows i0-4..i0+18 (23), cols j0-4..j0+34 (39); stride 41
    __shared__ float sd[2][23 * 41];
    // SINGLE-k column-sum records, SoA: entry e = i*39 + c
    __shared__ float csS1[624], csSb[624], csSbb[624], csT1[624], csTb[624];
    __shared__ float wsum[4];

    const float* src0 = pred + (size_t)b * (HH * WW);
    const float* src1 = gt   + (size_t)b * (HH * WW);
    for (int idx = tid; idx < 23 * 41; idx += 256) {
        int lr = idx / 41, lc = idx - lr * 41;
        int r = i0 - 4 + lr, c = j0 - 4 + lc;
        bool ok = (lc < 39) && (r >= 0) && (r < HH) && (c >= 0) && (c < WW);
        int off = r * WW + c;
        sd[0][idx] = ok ? src0[off] : 0.0f;
        sd[1][idx] = ok ? src1[off] : 0.0f;
    }

    // stage-2 per-thread constants (live across both phases)
    float aw[9];
#pragma unroll
    for (int m = 0; m < 9; ++m)
        aw[m] = ((float)(j0 + 2 * tx + m - 4) - 319.5f) * invFX;
    const float bc = ((float)(i0 + ty) - 239.5f) * invFY;
    const int ebase = ty * 39 + 2 * tx;   // record entry for m=0

    float n0A[3], n1A[3];   // input-0 normals for pixels 0,1
    float contrib = 0.0f;

    __syncthreads();

#pragma unroll
    for (int k = 0; k < 2; ++k) {
        // ---- stage 1 (phase k): 156 tasks = 39 cols x 4 row-groups ----
        // task: g = tid/39 in 0..3, c = tid%39, owns output rows 4g..4g+3
        // (init = 8-row sum at row 4g, then 3 slide-by-1 steps).
        if (tid < 156) {
            int g = tid / 39;
            int c = tid - 39 * g;
            int rb = 4 * g;
            const float* col = &sd[k][c];
            // bv of tile row rb (image row i0 + rb - 4)
            float bv = ((float)(i0 + rb - 4) - 239.5f) * invFY;
            float S1 = 0.f, Sb = 0.f, Sbb = 0.f, T1 = 0.f, Tb = 0.f;
#pragma unroll
            for (int r = 0; r < 8; ++r) {
                float d  = col[(rb + r) * 41];
                float bvr = fmaf((float)r, invFY, bv);
                float bd = bvr * d;
                T1 += d;  Tb += bd;
                S1  = fmaf(d,  d,  S1);
                Sb  = fmaf(bd, d,  Sb);
                Sbb = fmaf(bd, bd, Sbb);
            }
            int e = rb * 39 + c;
            csS1[e] = S1; csSb[e] = Sb; csSbb[e] = Sbb;
            csT1[e] = T1; csTb[e] = Tb;
#pragma unroll
            for (int s = 1; s < 4; ++s) {
                // window slides by 1: tile row rb+s-1 leaves, rb+s+7 enters
                float d0 = col[(rb + s - 1) * 41];
                float d1 = col[(rb + s + 7) * 41];
                float b0 = fmaf((float)(s - 1), invFY, bv);
                float b1 = fmaf((float)(s + 7), invFY, bv);
                float bd0 = b0 * d0, bd1 = b1 * d1;
                T1 += d1 - d0;
                Tb += bd1 - bd0;
                S1  += fmaf(d1,  d1,  -d0  * d0);
                Sb  += fmaf(bd1, d1,  -bd0 * d0);
                Sbb += fmaf(bd1, bd1, -bd0 * bd0);
                e += 39;
                csS1[e] = S1; csSb[e] = Sb; csSbb[e] = Sbb;
                csT1[e] = T1; csTb[e] = Tb;
            }
        }
        __syncthreads();

        // ---- stage 2 (phase k): shared-core combine + 2 f32 solves ----
        {
            float Sxx = 0.f, Sxy = 0.f, Sxz = 0.f, Syy = 0.f, Syz = 0.f;
            float Szz = 0.f, Sxs = 0.f, Sys = 0.f, Szs = 0.f;
#pragma unroll
            for (int m = 1; m < 8; ++m) {
                int e = ebase + m;
                float s1  = csS1[e];
                float sb  = csSb[e];
                float sbb = csSbb[e];
                float t1  = csT1[e];
                float tb  = csTb[e];
                Szz += s1;  Syz += sb;  Syy += sbb;
                Szs += t1;  Sys += tb;
                Sxz = fmaf(aw[m],         s1, Sxz);
                Sxy = fmaf(aw[m],         sb, Sxy);
                Sxs = fmaf(aw[m],         t1, Sxs);
                Sxx = fmaf(aw[m] * aw[m], s1, Sxx);
            }

            float nn[2][3];
#pragma unroll
            for (int p = 0; p < 2; ++p) {
                int m = (p == 0) ? 0 : 8;               // unique tap
                int e = ebase + m;
                float s1  = csS1[e];
                float sb  = csSb[e];
                float sbb = csSbb[e];
                float t1  = csT1[e];
                float tb  = csTb[e];
                float xx = fmaf(aw[m] * aw[m], s1, Sxx);
                float xy = fmaf(aw[m], sb, Sxy);
                float xz = fmaf(aw[m], s1, Sxz);
                float yy = Syy + sbb;
                float yz = Syz + sb;
                float zz = Szz + s1;
                float xs = fmaf(aw[m], t1, Sxs);
                float ys = Sys + tb;
                float zs = Szs + t1;
                float d0 = sd[k][(ty + 4) * 41 + (2 * tx + p + 4)];
                solve_normal(xx, xy, xz, yy, yz, zz, xs, ys, zs,
                             aw[4 + p], bc, d0, &nn[p][0], &nn[p][1], &nn[p][2]);
            }
            if (k == 0) {
                n0A[0] = nn[0][0]; n0A[1] = nn[0][1]; n0A[2] = nn[0][2];
                n1A[0] = nn[1][0]; n1A[1] = nn[1][1]; n1A[2] = nn[1][2];
                __syncthreads();   // all cs reads done -> phase 1 may overwrite
            } else {
                const int i = i0 + ty;
                const bool valid0 = (i < HH);
                const bool valid1 = (i < HH) && (j0 + 2 * tx + 1 < WW);
                float c0 = fabsf(n0A[0] - nn[0][0]) + fabsf(n0A[1] - nn[0][1])
                         + fabsf(n0A[2] - nn[0][2]);
                float c1 = fabsf(n1A[0] - nn[1][0]) + fabsf(n1A[1] - nn[1][1])
                         + fabsf(n1A[2] - nn[1][2]);
                contrib = (valid0 ? c0 : 0.0f) + (valid1 ? c1 : 0.0f);
            }
        }
    }

    // ---- reduce: wave shuffle -> LDS -> ONE plain STORE per block ----
    float v = contrib;
#pragma unroll
    for (int off = 32; off > 0; off >>= 1) v += __shfl_down(v, off, 64);
    int wid = tid >> 6, lane = tid & 63;
    if (lane == 0) wsum[wid] = v;
    __syncthreads();
    if (tid == 0) {
        double bs = (double)wsum[0] + (double)wsum[1] + (double)wsum[2] + (double)wsum[3];
        int slot = blockIdx.x + 20 * blockIdx.y + 600 * blockIdx.z;
        acc[slot] = bs;   // unique slot, written every launch -> no memset
    }
}

__global__ void ppal_finalize(const double* __restrict__ acc, float* __restrict__ out)
{
    int tid = threadIdx.x;             // 256 threads, one block
    double v = 0.0;
    for (int s = tid; s < NBLK; s += 256) v += acc[s];
#pragma unroll
    for (int off = 32; off > 0; off >>= 1) v += __shfl_down(v, off, 64);
    __shared__ double wsum[4];
    int wid = tid >> 6, lane = tid & 63;
    if (lane == 0) wsum[wid] = v;
    __syncthreads();
    if (tid == 0)
        out[0] = (float)((wsum[0] + wsum[1] + wsum[2] + wsum[3])
                         * (1.0 / 7345944.0));  // mean over B*3*H*W
}

extern "C" void kernel_launch(void* const* d_in, const int* in_sizes, int n_in,
                              void* d_out, int out_size, void* d_ws, size_t ws_size,
                              hipStream_t stream)
{
    const float* pred = (const float*)d_in[0];
    const float* gt   = (const float*)d_in[1];
    float* out  = (float*)d_out;
    double* acc = (double*)d_ws;

    dim3 grid(20, 30, BATCH);          // 32-col x 16-row tiles = 4800 blocks
    dim3 block(16, 16);
    ppal_main<<<grid, block, 0, stream>>>(pred, gt, acc);
    ppal_finalize<<<1, 256, 0, stream>>>(acc, out);
}

// Round 3
// 98.240 us; speedup vs baseline: 1.0856x; 1.0089x over previous
//
#include <hip/hip_runtime.h>

#define HH 479
#define WW 639
#define BATCH 8
#define NBLK (20 * 30 * 8)   // 4800 blocks

// Tile: 32 cols x 16 rows per block, 256 threads, 2 px/thread.
// R13: column-sum record packed as float4{S1,Sb,Sbb,T1} (+ float Tb array).
// Per record: ds_read_b128 + ds_read_b32 (2 instr) instead of 5x b32 ->
// stage-2 LDS instr/thread/phase 47 -> 20; stage-1 writes 5 -> 2 per record.
// Bank check: b128 quad q=(7ty+2tx+m) mod 8 -> exactly 8 lanes/quad = the
// b128 conflict-free floor; Tb b32 keeps odd ty-stride 39 -> 2-way max
// (free, m136). LDS total still ~20 KB -> 8 blocks/CU (32 waves, max occ).
// R12: k-phased cs (one buffer reused for pred/gt phases); stage 1 = 156
// tasks (39 cols x 4 row-groups), init 8-row sum + 3 slide-by-1; sd row
// stride 41 (odd). R8: adjacent px share 7/8 window cols -> 9 shared core
// sums + 1 unique tap. Solve (f32, R5-validated): centered A_hat +
// Sherman-Morrison => same unit normal as (M+eps I)^-1 s.
// Retirement: per-block STORE into acc[block_id] (no memset), tiny finalize.
// (R2/R3: fence+counter readback poisons retirement.)

__device__ __forceinline__ void solve_normal(
    float xx, float xy, float xz, float yy, float yz, float zz,
    float xs, float ys, float zs,
    float a_c, float b_c, float d0,
    float* nx, float* ny, float* nz)
{
    const float EPSV = 1e-6f;
    const float inv64 = 1.0f / 64.0f;
    float hx = xs * inv64, hy = ys * inv64, hz = zs * inv64;
    float cxx = fmaf(-hx, xs, xx) + EPSV;
    float cxy = fmaf(-hx, ys, xy);
    float cxz = fmaf(-hx, zs, xz);
    float cyy = fmaf(-hy, ys, yy) + EPSV;
    float cyz = fmaf(-hy, zs, yz);
    float czz = fmaf(-hz, zs, zz) + EPSV;
    float c00 = fmaf(cyy, czz, -cyz * cyz);
    float c01 = fmaf(cxz, cyz, -cxy * czz);
    float c02 = fmaf(cxy, cyz, -cxz * cyy);
    float c11 = fmaf(cxx, czz, -cxz * cxz);
    float c12 = fmaf(cxy, cxz, -cxx * cyz);
    float c22 = fmaf(cxx, cyy, -cxy * cxy);
    float m0 = fmaf(c00, xs, fmaf(c01, ys, c02 * zs));
    float m1 = fmaf(c01, xs, fmaf(c11, ys, c12 * zs));
    float m2 = fmaf(c02, xs, fmaf(c12, ys, c22 * zs));
    float g  = fmaf(m0, a_c, fmaf(m1, b_c, m2));   // sign of dot(n, xyz), d0>0
    float inv = rsqrtf(fmaf(m0, m0, fmaf(m1, m1, m2 * m2)));
    if (g > 0.0f) inv = -inv;
    if (!(d0 > 0.0f)) inv = 0.0f;                  // where(depth>0, n, 0)
    *nx = m0 * inv; *ny = m1 * inv; *nz = m2 * inv;
}

__global__ __launch_bounds__(256, 8)
void ppal_main(const float* __restrict__ pred, const float* __restrict__ gt,
               double* __restrict__ acc)
{
    const int tx = threadIdx.x;        // 0..15
    const int ty = threadIdx.y;        // 0..15
    const int tid = ty * 16 + tx;
    const int j0 = blockIdx.x * 32;
    const int i0 = blockIdx.y * 16;
    const int b  = blockIdx.z;

    const float invFX = 1.0f / 518.857f;
    const float invFY = 1.0f / 519.469f;

    // depth tiles: rows i0-4..i0+18 (23), cols j0-4..j0+34 (39); stride 41
    __shared__ float sd[2][23 * 41];
    // SINGLE-k column-sum records: cs4[e] = {S1,Sb,Sbb,T1}, csTb[e] = Tb,
    // entry e = i*39 + c
    __shared__ float4 cs4[624];
    __shared__ float  csTb[624];
    __shared__ float  wsum[4];

    const float* src0 = pred + (size_t)b * (HH * WW);
    const float* src1 = gt   + (size_t)b * (HH * WW);
    for (int idx = tid; idx < 23 * 41; idx += 256) {
        int lr = idx / 41, lc = idx - lr * 41;
        int r = i0 - 4 + lr, c = j0 - 4 + lc;
        bool ok = (lc < 39) && (r >= 0) && (r < HH) && (c >= 0) && (c < WW);
        int off = r * WW + c;
        sd[0][idx] = ok ? src0[off] : 0.0f;
        sd[1][idx] = ok ? src1[off] : 0.0f;
    }

    // stage-2 per-thread constants (live across both phases)
    float aw[9];
#pragma unroll
    for (int m = 0; m < 9; ++m)
        aw[m] = ((float)(j0 + 2 * tx + m - 4) - 319.5f) * invFX;
    const float bc = ((float)(i0 + ty) - 239.5f) * invFY;
    const int ebase = ty * 39 + 2 * tx;   // record entry for m=0

    float n0A[3], n1A[3];   // input-0 normals for pixels 0,1
    float contrib = 0.0f;

    __syncthreads();

#pragma unroll
    for (int k = 0; k < 2; ++k) {
        // ---- stage 1 (phase k): 156 tasks = 39 cols x 4 row-groups ----
        // task: g = tid/39 in 0..3, c = tid%39, owns output rows 4g..4g+3
        // (init = 8-row sum at row 4g, then 3 slide-by-1 steps).
        if (tid < 156) {
            int g = tid / 39;
            int c = tid - 39 * g;
            int rb = 4 * g;
            const float* col = &sd[k][c];
            // bv of tile row rb (image row i0 + rb - 4)
            float bv = ((float)(i0 + rb - 4) - 239.5f) * invFY;
            float S1 = 0.f, Sb = 0.f, Sbb = 0.f, T1 = 0.f, Tb = 0.f;
#pragma unroll
            for (int r = 0; r < 8; ++r) {
                float d  = col[(rb + r) * 41];
                float bvr = fmaf((float)r, invFY, bv);
                float bd = bvr * d;
                T1 += d;  Tb += bd;
                S1  = fmaf(d,  d,  S1);
                Sb  = fmaf(bd, d,  Sb);
                Sbb = fmaf(bd, bd, Sbb);
            }
            int e = rb * 39 + c;
            cs4[e]  = make_float4(S1, Sb, Sbb, T1);
            csTb[e] = Tb;
#pragma unroll
            for (int s = 1; s < 4; ++s) {
                // window slides by 1: tile row rb+s-1 leaves, rb+s+7 enters
                float d0 = col[(rb + s - 1) * 41];
                float d1 = col[(rb + s + 7) * 41];
                float b0 = fmaf((float)(s - 1), invFY, bv);
                float b1 = fmaf((float)(s + 7), invFY, bv);
                float bd0 = b0 * d0, bd1 = b1 * d1;
                T1 += d1 - d0;
                Tb += bd1 - bd0;
                S1  += fmaf(d1,  d1,  -d0  * d0);
                Sb  += fmaf(bd1, d1,  -bd0 * d0);
                Sbb += fmaf(bd1, bd1, -bd0 * bd0);
                e += 39;
                cs4[e]  = make_float4(S1, Sb, Sbb, T1);
                csTb[e] = Tb;
            }
        }
        __syncthreads();

        // ---- stage 2 (phase k): shared-core combine + 2 f32 solves ----
        {
            float Sxx = 0.f, Sxy = 0.f, Sxz = 0.f, Syy = 0.f, Syz = 0.f;
            float Szz = 0.f, Sxs = 0.f, Sys = 0.f, Szs = 0.f;
#pragma unroll
            for (int m = 1; m < 8; ++m) {
                int e = ebase + m;
                float4 r = cs4[e];           // {S1, Sb, Sbb, T1}
                float  tb = csTb[e];
                Szz += r.x;  Syz += r.y;  Syy += r.z;
                Szs += r.w;  Sys += tb;
                Sxz = fmaf(aw[m],         r.x, Sxz);
                Sxy = fmaf(aw[m],         r.y, Sxy);
                Sxs = fmaf(aw[m],         r.w, Sxs);
                Sxx = fmaf(aw[m] * aw[m], r.x, Sxx);
            }

            float nn[2][3];
#pragma unroll
            for (int p = 0; p < 2; ++p) {
                int m = (p == 0) ? 0 : 8;               // unique tap
                int e = ebase + m;
                float4 r = cs4[e];
                float  tb = csTb[e];
                float xx = fmaf(aw[m] * aw[m], r.x, Sxx);
                float xy = fmaf(aw[m], r.y, Sxy);
                float xz = fmaf(aw[m], r.x, Sxz);
                float yy = Syy + r.z;
                float yz = Syz + r.y;
                float zz = Szz + r.x;
                float xs = fmaf(aw[m], r.w, Sxs);
                float ys = Sys + tb;
                float zs = Szs + r.w;
                float d0 = sd[k][(ty + 4) * 41 + (2 * tx + p + 4)];
                solve_normal(xx, xy, xz, yy, yz, zz, xs, ys, zs,
                             aw[4 + p], bc, d0, &nn[p][0], &nn[p][1], &nn[p][2]);
            }
            if (k == 0) {
                n0A[0] = nn[0][0]; n0A[1] = nn[0][1]; n0A[2] = nn[0][2];
                n1A[0] = nn[1][0]; n1A[1] = nn[1][1]; n1A[2] = nn[1][2];
                __syncthreads();   // all cs reads done -> phase 1 may overwrite
            } else {
                const int i = i0 + ty;
                const bool valid0 = (i < HH);
                const bool valid1 = (i < HH) && (j0 + 2 * tx + 1 < WW);
                float c0 = fabsf(n0A[0] - nn[0][0]) + fabsf(n0A[1] - nn[0][1])
                         + fabsf(n0A[2] - nn[0][2]);
                float c1 = fabsf(n1A[0] - nn[1][0]) + fabsf(n1A[1] - nn[1][1])
                         + fabsf(n1A[2] - nn[1][2]);
                contrib = (valid0 ? c0 : 0.0f) + (valid1 ? c1 : 0.0f);
            }
        }
    }

    // ---- reduce: wave shuffle -> LDS -> ONE plain STORE per block ----
    float v = contrib;
#pragma unroll
    for (int off = 32; off > 0; off >>= 1) v += __shfl_down(v, off, 64);
    int wid = tid >> 6, lane = tid & 63;
    if (lane == 0) wsum[wid] = v;
    __syncthreads();
    if (tid == 0) {
        double bs = (double)wsum[0] + (double)wsum[1] + (double)wsum[2] + (double)wsum[3];
        int slot = blockIdx.x + 20 * blockIdx.y + 600 * blockIdx.z;
        acc[slot] = bs;   // unique slot, written every launch -> no memset
    }
}

__global__ void ppal_finalize(const double* __restrict__ acc, float* __restrict__ out)
{
    int tid = threadIdx.x;             // 256 threads, one block
    double v = 0.0;
    for (int s = tid; s < NBLK; s += 256) v += acc[s];
#pragma unroll
    for (int off = 32; off > 0; off >>= 1) v += __shfl_down(v, off, 64);
    __shared__ double wsum[4];
    int wid = tid >> 6, lane = tid & 63;
    if (lane == 0) wsum[wid] = v;
    __syncthreads();
    if (tid == 0)
        out[0] = (float)((wsum[0] + wsum[1] + wsum[2] + wsum[3])
                         * (1.0 / 7345944.0));  // mean over B*3*H*W
}

extern "C" void kernel_launch(void* const* d_in, const int* in_sizes, int n_in,
                              void* d_out, int out_size, void* d_ws, size_t ws_size,
                              hipStream_t stream)
{
    const float* pred = (const float*)d_in[0];
    const float* gt   = (const float*)d_in[1];
    float* out  = (float*)d_out;
    double* acc = (double*)d_ws;

    dim3 grid(20, 30, BATCH);          // 32-col x 16-row tiles = 4800 blocks
    dim3 block(16, 16);
    ppal_main<<<grid, block, 0, stream>>>(pred, gt, acc);
    ppal_finalize<<<1, 256, 0, stream>>>(acc, out);
}